// Round 5
// baseline (110.745 us; speedup 1.0000x reference)
//
#include <hip/hip_runtime.h>
#include <hip/hip_bf16.h>

#define H 768
#define SEQ 256
#define NPAIR 32896                // S*(S+1)/2 = 257*128
#define NOUTP 160
#define OFF_H2H 263168u            // 4*32896*2
#define OFF_T2T 9737216u           // OFF_H2H + 4*24*32896*3

#define N_BPK 122880               // 24 k32-steps * 10 frags * 64 lanes * 8 bf16
#define N_FCW 1179648              // 1536*768
#define SCL 2.8853900817779268f    // 2*log2(e): pre-scale L/R so stage tanh needs no mul

typedef short bf16x8 __attribute__((ext_vector_type(8)));
typedef float f32x4 __attribute__((ext_vector_type(4)));

__device__ __forceinline__ float tanh_s(float xs) {
    // xs = 2*log2(e)*x  ->  tanh(x) = 1 - 2/(exp2(xs)+1). 2 VALU + 2 trans.
    float e = __builtin_amdgcn_exp2f(xs);
    return fmaf(-2.0f, __builtin_amdgcn_rcpf(e + 1.0f), 1.0f);
}
__device__ __forceinline__ float bf_lo(int w){ return __uint_as_float(((unsigned)w) << 16); }
__device__ __forceinline__ float bf_hi(int w){ return __uint_as_float(((unsigned)w) & 0xffff0000u); }
__device__ __forceinline__ int cvtpk(float lo, float hi) {
    int r;
    asm("v_cvt_pk_bf16_f32 %0, %1, %2" : "=v"(r) : "v"(lo), "v"(hi));
    return r;
}
__device__ __forceinline__ unsigned short bf16r(float x){
    unsigned int u = __float_as_uint(x);
    u += 0x7fffu + ((u >> 16) & 1u);
    return (unsigned short)(u >> 16);
}
__device__ __forceinline__ int4 tanh_pack(int4 lv, int4 rv) {
    int4 st;
    st.x = cvtpk(tanh_s(bf_lo(lv.x) + bf_lo(rv.x)), tanh_s(bf_hi(lv.x) + bf_hi(rv.x)));
    st.y = cvtpk(tanh_s(bf_lo(lv.y) + bf_lo(rv.y)), tanh_s(bf_hi(lv.y) + bf_hi(rv.y)));
    st.z = cvtpk(tanh_s(bf_lo(lv.z) + bf_lo(rv.z)), tanh_s(bf_hi(lv.z) + bf_hi(rv.z)));
    st.w = cvtpk(tanh_s(bf_lo(lv.w) + bf_lo(rv.w)), tanh_s(bf_hi(lv.w) + bf_hi(rv.w)));
    return st;
}

__device__ __forceinline__ int row_start(int i) { return i * SEQ - (i * (i - 1)) / 2; }
__device__ __forceinline__ void pair_ij(int p, int& oi, int& oj) {
    double disc = 263169.0 - 8.0 * (double)p;   // (2S+1)^2 - 8p
    int i = (int)((513.0 - sqrt(disc)) * 0.5);
    if (i > 0 && row_start(i) > p) --i;
    while (row_start(i + 1) <= p) ++i;
    oi = i;
    oj = i + (p - row_start(i));
}

// ---------------- kernel 0: pack Bpk (fragment-ordered), fcwb, bc ----------------
// Bpk linear idx = ((k32*10 + f)*64 + lane)*8 + j -> W[n=f*16+(lane&15)][k=k32*32+(lane>>4)*8+j]
__global__ __launch_bounds__(256) void pack_kernel(
    const float* __restrict__ h2t_w, const float* __restrict__ h2h_w,
    const float* __restrict__ t2t_w, const float* __restrict__ h2t_b,
    const float* __restrict__ h2h_b, const float* __restrict__ t2t_b,
    const float* __restrict__ fc_w,
    unsigned short* __restrict__ Bpk, unsigned short* __restrict__ fcwb,
    float* __restrict__ bc)
{
    int idx = blockIdx.x * 256 + threadIdx.x;
    if (idx < N_BPK) {
        int j = idx & 7, lane = (idx >> 3) & 63, rest = idx >> 9;
        int f = rest % 10, k32 = rest / 10;
        int n = f * 16 + (lane & 15);
        int k = k32 * 32 + ((lane >> 4) << 3) + j;
        float v = 0.f;
        if (n < 2)        v = h2t_w[n * H + k];
        else if (n < 74)  v = h2h_w[(n - 2) * H + k];
        else if (n < 146) v = t2t_w[(n - 74) * H + k];
        Bpk[idx] = bf16r(v);
    } else if (idx < N_BPK + N_FCW) {
        int q = idx - N_BPK;
        int n = q / H, k = q % H;          // n in [0,1536): 0..767 -> Wl, 768.. -> Wr
        float v = (n < H) ? fc_w[(size_t)n * 2 * H + k]
                          : fc_w[(size_t)(n - H) * 2 * H + H + k];
        fcwb[q] = bf16r(v);
    } else if (idx < N_BPK + N_FCW + NOUTP) {
        int q = idx - N_BPK - N_FCW;
        float v = 0.f;
        if (q < 2)        v = h2t_b[q];
        else if (q < 74)  v = h2h_b[q - 2];
        else if (q < 146) v = t2t_b[q - 74];
        bc[q] = v;
    }
}

// ---------------- kernel 1: LB/RB = hidden @ fc_w (bf16 MFMA GEMM), pre-scaled by SCL ----------------
__global__ __launch_bounds__(256, 2) void lr_mfma(
    const float* __restrict__ hidden, const unsigned short* __restrict__ fcwb,
    const float* __restrict__ fc_b,
    unsigned short* __restrict__ LB, unsigned short* __restrict__ RB)
{
    __shared__ __align__(16) char sm[24576];          // A 8KB | B 16KB
    const int tid = threadIdx.x, l = tid & 63, w = tid >> 6;
    const int wm = w >> 1, wn = w & 1;
    const int m0 = blockIdx.x * 64, n0 = blockIdx.y * 128;
    f32x4 acc[2][4] = {};
    for (int c = 0; c < 12; ++c) {
        const int k0 = c * 64;
        #pragma unroll
        for (int it = 0; it < 2; ++it) {              // A: 64 rows x 64 k, cvt f32->bf16
            int idx = tid + it * 256;
            int row = idx >> 3, k8 = idx & 7;
            const float4* src = reinterpret_cast<const float4*>(hidden + (size_t)(m0 + row) * H + k0 + k8 * 8);
            float4 a = src[0], bq = src[1];
            int4 st;
            st.x = cvtpk(a.x, a.y);  st.y = cvtpk(a.z, a.w);
            st.z = cvtpk(bq.x, bq.y); st.w = cvtpk(bq.z, bq.w);
            *reinterpret_cast<int4*>(sm + row * 128 + ((k8 * 16) ^ ((row & 7) << 4))) = st;
        }
        #pragma unroll
        for (int it = 0; it < 4; ++it) {              // B: 128 rows x 64 k
            int idx = tid + it * 256;
            int row = idx >> 3, k8 = idx & 7;
            *reinterpret_cast<int4*>(sm + 8192 + row * 128 + ((k8 * 16) ^ ((row & 7) << 4))) =
                *reinterpret_cast<const int4*>(fcwb + (size_t)(n0 + row) * H + k0 + k8 * 8);
        }
        __syncthreads();
        #pragma unroll
        for (int kk = 0; kk < 2; ++kk) {
            const int sl = kk * 4 + (l >> 4);
            const int swz = (l & 7) << 4;
            bf16x8 af[2], bfr[4];
            #pragma unroll
            for (int a = 0; a < 2; ++a) {
                int row = 32 * wm + 16 * a + (l & 15);
                af[a] = *reinterpret_cast<const bf16x8*>(sm + row * 128 + ((sl * 16) ^ swz));
            }
            #pragma unroll
            for (int f = 0; f < 4; ++f) {
                int row = 64 * wn + 16 * f + (l & 15);
                bfr[f] = *reinterpret_cast<const bf16x8*>(sm + 8192 + row * 128 + ((sl * 16) ^ swz));
            }
            #pragma unroll
            for (int a = 0; a < 2; ++a)
                #pragma unroll
                for (int f = 0; f < 4; ++f)
                    acc[a][f] = __builtin_amdgcn_mfma_f32_16x16x32_bf16(af[a], bfr[f], acc[a][f], 0, 0, 0);
        }
        __syncthreads();
    }
    #pragma unroll
    for (int a = 0; a < 2; ++a)
        #pragma unroll
        for (int f = 0; f < 4; ++f)
            #pragma unroll
            for (int r = 0; r < 4; ++r) {
                int row = m0 + 32 * wm + 16 * a + 4 * (l >> 4) + r;
                int col = n0 + 64 * wn + 16 * f + (l & 15);
                float v = acc[a][f][r];
                if (n0 < H) LB[(size_t)row * H + col] = bf16r((v + fc_b[col]) * SCL);
                else        RB[(size_t)row * H + (col - H)] = bf16r(v * SCL);
            }
}

// ---------------- kernel 2: linear-pair MFMA, 1 barrier/chunk, A dbuf LDS, B in regs ----------------
// block = 512 thr (8 waves = 4 wm x 2 wn), M-tile = 128 pairs, N = 160, chunk = 64 k
__global__ __launch_bounds__(512) void pair_mfma(
    const unsigned short* __restrict__ LB, const unsigned short* __restrict__ RB,
    const unsigned short* __restrict__ Bpk, const float* __restrict__ bc,
    float* __restrict__ out)
{
    __shared__ __align__(16) char sm[34432];
    // A buf0 [0,16384) | buf1 [16384,32768) | iOf [32768,33280) | jOf [33280,33792) | bc_s [33792,34432)
    // epilogue: scores [32][172] f32 alias at [0,22016)
    int*   iOf  = reinterpret_cast<int*>(sm + 32768);
    int*   jOf  = reinterpret_cast<int*>(sm + 33280);
    float* bc_s = reinterpret_cast<float*>(sm + 33792);

    const int tid = threadIdx.x, l = tid & 63, w = tid >> 6;
    const int wm = w >> 1, wn = w & 1;
    const int b = blockIdx.y, p0 = blockIdx.x * 128;

    if (tid < 128) {
        int i, j; pair_ij(p0 + tid, i, j);
        iOf[tid] = i * H; jOf[tid] = j * H;
    }
    if (tid < NOUTP) bc_s[tid] = bc[tid];
    __syncthreads();

    const unsigned short* LBb = LB + (size_t)b * SEQ * H;
    const unsigned short* RBb = RB + (size_t)b * SEQ * H;
    const int qA = tid >> 3, k8 = tid & 7;
    const unsigned short* lpA = LBb + iOf[qA] + k8 * 8;       // rows qA / qA+64, const per thread
    const unsigned short* rpA = RBb + jOf[qA] + k8 * 8;
    const unsigned short* lpB = LBb + iOf[qA + 64] + k8 * 8;
    const unsigned short* rpB = RBb + jOf[qA + 64] + k8 * 8;
    const int stoff = qA * 128 + ((k8 * 16) ^ ((qA & 7) << 4));
    const unsigned short* bqp = Bpk + wn * 2560 + l * 8;      // per-lane B fragment base

    f32x4 acc[2][5] = {};

    {   // prologue: stage chunk 0 into buf0
        int4 lA = *reinterpret_cast<const int4*>(lpA);
        int4 rA = *reinterpret_cast<const int4*>(rpA);
        int4 lB = *reinterpret_cast<const int4*>(lpB);
        int4 rB = *reinterpret_cast<const int4*>(rpB);
        *reinterpret_cast<int4*>(sm + stoff)        = tanh_pack(lA, rA);
        *reinterpret_cast<int4*>(sm + stoff + 8192) = tanh_pack(lB, rB);
    }
    __syncthreads();

    for (int c = 0; c < 12; ++c) {
        char* bufc = sm + ((c & 1) << 14);
        char* bufn = sm + (((c + 1) & 1) << 14);
        // 1) issue next-chunk L/R loads (oldest in flight -> counted vmcnt at tanh)
        const int off = (c < 11 ? (c + 1) : c) * 64;
        int4 nlA = *reinterpret_cast<const int4*>(lpA + off);
        int4 nrA = *reinterpret_cast<const int4*>(rpA + off);
        int4 nlB = *reinterpret_cast<const int4*>(lpB + off);
        int4 nrB = *reinterpret_cast<const int4*>(rpB + off);
        // 2) issue B group 0 (kk=0 frags)
        const unsigned short* bqc = bqp + c * 10240;
        bf16x8 bq0 = *reinterpret_cast<const bf16x8*>(bqc);
        bf16x8 bq1 = *reinterpret_cast<const bf16x8*>(bqc + 512);
        bf16x8 bq2 = *reinterpret_cast<const bf16x8*>(bqc + 1024);
        bf16x8 bq3 = *reinterpret_cast<const bf16x8*>(bqc + 1536);
        bf16x8 bq4 = *reinterpret_cast<const bf16x8*>(bqc + 2048);
        // 3) tanh+pack next chunk -> buf^1 (waits only the nl loads)
        if (c < 11) {
            *reinterpret_cast<int4*>(bufn + stoff)        = tanh_pack(nlA, nrA);
            *reinterpret_cast<int4*>(bufn + stoff + 8192) = tanh_pack(nlB, nrB);
        }
        // 4) issue B group 1 (kk=1 frags)
        bf16x8 bq5 = *reinterpret_cast<const bf16x8*>(bqc + 5120);
        bf16x8 bq6 = *reinterpret_cast<const bf16x8*>(bqc + 5632);
        bf16x8 bq7 = *reinterpret_cast<const bf16x8*>(bqc + 6144);
        bf16x8 bq8 = *reinterpret_cast<const bf16x8*>(bqc + 6656);
        bf16x8 bq9 = *reinterpret_cast<const bf16x8*>(bqc + 7168);
        // 5) MFMA: kk = 0
        {
            const int sl16 = (l >> 4) << 4;
            const int swz = (l & 7) << 4;
            const int r0 = (32 * wm + (l & 15)) * 128;
            bf16x8 af0 = *reinterpret_cast<const bf16x8*>(bufc + r0 + (sl16 ^ swz));
            bf16x8 af1 = *reinterpret_cast<const bf16x8*>(bufc + r0 + 2048 + (sl16 ^ swz));
            acc[0][0] = __builtin_amdgcn_mfma_f32_16x16x32_bf16(af0, bq0, acc[0][0], 0, 0, 0);
            acc[1][0] = __builtin_amdgcn_mfma_f32_16x16x32_bf16(af1, bq0, acc[1][0], 0, 0, 0);
            acc[0][1] = __builtin_amdgcn_mfma_f32_16x16x32_bf16(af0, bq1, acc[0][1], 0, 0, 0);
            acc[1][1] = __builtin_amdgcn_mfma_f32_16x16x32_bf16(af1, bq1, acc[1][1], 0, 0, 0);
            acc[0][2] = __builtin_amdgcn_mfma_f32_16x16x32_bf16(af0, bq2, acc[0][2], 0, 0, 0);
            acc[1][2] = __builtin_amdgcn_mfma_f32_16x16x32_bf16(af1, bq2, acc[1][2], 0, 0, 0);
            acc[0][3] = __builtin_amdgcn_mfma_f32_16x16x32_bf16(af0, bq3, acc[0][3], 0, 0, 0);
            acc[1][3] = __builtin_amdgcn_mfma_f32_16x16x32_bf16(af1, bq3, acc[1][3], 0, 0, 0);
            acc[0][4] = __builtin_amdgcn_mfma_f32_16x16x32_bf16(af0, bq4, acc[0][4], 0, 0, 0);
            acc[1][4] = __builtin_amdgcn_mfma_f32_16x16x32_bf16(af1, bq4, acc[1][4], 0, 0, 0);
        }
        // 6) MFMA: kk = 1
        {
            const int sl16 = (4 + (l >> 4)) << 4;
            const int swz = (l & 7) << 4;
            const int r0 = (32 * wm + (l & 15)) * 128;
            bf16x8 af0 = *reinterpret_cast<const bf16x8*>(bufc + r0 + (sl16 ^ swz));
            bf16x8 af1 = *reinterpret_cast<const bf16x8*>(bufc + r0 + 2048 + (sl16 ^ swz));
            acc[0][0] = __builtin_amdgcn_mfma_f32_16x16x32_bf16(af0, bq5, acc[0][0], 0, 0, 0);
            acc[1][0] = __builtin_amdgcn_mfma_f32_16x16x32_bf16(af1, bq5, acc[1][0], 0, 0, 0);
            acc[0][1] = __builtin_amdgcn_mfma_f32_16x16x32_bf16(af0, bq6, acc[0][1], 0, 0, 0);
            acc[1][1] = __builtin_amdgcn_mfma_f32_16x16x32_bf16(af1, bq6, acc[1][1], 0, 0, 0);
            acc[0][2] = __builtin_amdgcn_mfma_f32_16x16x32_bf16(af0, bq7, acc[0][2], 0, 0, 0);
            acc[1][2] = __builtin_amdgcn_mfma_f32_16x16x32_bf16(af1, bq7, acc[1][2], 0, 0, 0);
            acc[0][3] = __builtin_amdgcn_mfma_f32_16x16x32_bf16(af0, bq8, acc[0][3], 0, 0, 0);
            acc[1][3] = __builtin_amdgcn_mfma_f32_16x16x32_bf16(af1, bq8, acc[1][3], 0, 0, 0);
            acc[0][4] = __builtin_amdgcn_mfma_f32_16x16x32_bf16(af0, bq9, acc[0][4], 0, 0, 0);
            acc[1][4] = __builtin_amdgcn_mfma_f32_16x16x32_bf16(af1, bq9, acc[1][4], 0, 0, 0);
        }
        __syncthreads();
    }

    // epilogue: 4 steps of 32 rows; wave-group wm==s writes its scores, all waves do softmax
    float* scw = reinterpret_cast<float*>(sm);               // [32][172]
    for (int s = 0; s < 4; ++s) {
        if (wm == s) {
            #pragma unroll
            for (int m = 0; m < 2; ++m)
                #pragma unroll
                for (int f = 0; f < 5; ++f)
                    #pragma unroll
                    for (int r = 0; r < 4; ++r) {
                        int rl = 16 * m + 4 * (l >> 4) + r;
                        int col = 80 * wn + 16 * f + (l & 15);
                        scw[rl * 172 + col] = acc[m][f][r];
                    }
        }
        __syncthreads();
        if (tid < 64) {                                      // h2t: 32 rows x 2
            int rl = tid >> 1, tt = tid & 1;
            int p = p0 + 32 * s + rl;
            out[((size_t)b * NPAIR + p) * 2 + tt] = scw[rl * 172 + tt] + bc_s[tt];
        }
        #pragma unroll
        for (int it = 0; it < 3; ++it) {                     // 32 rows x 48 triples
            int item = it * 512 + tid;
            int rl = item & 31, rr = item >> 5;
            int ob = 2 + rr * 3;
            float l0 = scw[rl * 172 + ob + 0] + bc_s[ob + 0];
            float l1 = scw[rl * 172 + ob + 1] + bc_s[ob + 1];
            float l2 = scw[rl * 172 + ob + 2] + bc_s[ob + 2];
            float mx = fmaxf(l0, fmaxf(l1, l2));
            float e0 = __expf(l0 - mx), e1 = __expf(l1 - mx), e2 = __expf(l2 - mx);
            float inv = __fdividef(1.0f, e0 + e1 + e2);
            int p = p0 + 32 * s + rl;
            size_t base = (rr < 24)
                ? (size_t)OFF_H2H + ((size_t)(b * 24 + rr) * NPAIR + p) * 3
                : (size_t)OFF_T2T + ((size_t)(b * 24 + rr - 24) * NPAIR + p) * 3;
            out[base + 0] = e0 * inv;
            out[base + 1] = e1 * inv;
            out[base + 2] = e2 * inv;
        }
        __syncthreads();
    }
}

extern "C" void kernel_launch(void* const* d_in, const int* in_sizes, int n_in,
                              void* d_out, int out_size, void* d_ws, size_t ws_size,
                              hipStream_t stream) {
    const float* hidden = (const float*)d_in[0];
    const float* fc_w   = (const float*)d_in[1];
    const float* fc_b   = (const float*)d_in[2];
    const float* h2t_w  = (const float*)d_in[3];
    const float* h2t_b  = (const float*)d_in[4];
    const float* h2h_w  = (const float*)d_in[5];
    const float* h2h_b  = (const float*)d_in[6];
    const float* t2t_w  = (const float*)d_in[7];
    const float* t2t_b  = (const float*)d_in[8];

    char* wsb = (char*)d_ws;
    unsigned short* LBw  = (unsigned short*)(wsb);              // 1024*768 bf16 = 1.5 MB
    unsigned short* RBw  = (unsigned short*)(wsb + 1572864);    // 1.5 MB
    unsigned short* Bpk  = (unsigned short*)(wsb + 3145728);    // 240 KB
    unsigned short* fcwb = (unsigned short*)(wsb + 3391488);    // 2.25 MB
    float*          bc   = (float*)        (wsb + 5750784);     // 640 B

    float* out = (float*)d_out;

    pack_kernel<<<(N_BPK + N_FCW + NOUTP + 255) / 256, 256, 0, stream>>>(
        h2t_w, h2h_w, t2t_w, h2t_b, h2h_b, t2t_b, fc_w, Bpk, fcwb, bc);
    lr_mfma<<<dim3(16, 12), 256, 0, stream>>>(hidden, fcwb, fc_b, LBw, RBw);
    pair_mfma<<<dim3(NPAIR / 128, 4), 512, 0, stream>>>(LBw, RBw, Bpk, bc, out);
}

// Round 6
// 96.467 us; speedup vs baseline: 1.1480x; 1.1480x over previous
//
#include <hip/hip_runtime.h>
#include <hip/hip_bf16.h>

#define H 768
#define SEQ 256
#define NPAIR 32896                // S*(S+1)/2 = 257*128
#define NOUTP 160
#define OFF_H2H 263168u            // 4*32896*2
#define OFF_T2T 9737216u           // OFF_H2H + 4*24*32896*3

#define N_BPK 122880               // 24 k32-steps * 10 frags * 64 lanes * 8 bf16
#define N_FCW 1179648              // 1536*768
#define SCL 2.8853900817779268f    // 2*log2(e): pre-scale L/R so stage tanh needs no mul

typedef short bf16x8 __attribute__((ext_vector_type(8)));
typedef float f32x4 __attribute__((ext_vector_type(4)));

__device__ __forceinline__ float tanh_s(float xs) {
    // xs = 2*log2(e)*x  ->  tanh(x) = 1 - 2/(exp2(xs)+1). 2 VALU + 2 trans.
    float e = __builtin_amdgcn_exp2f(xs);
    return fmaf(-2.0f, __builtin_amdgcn_rcpf(e + 1.0f), 1.0f);
}
__device__ __forceinline__ float bf_lo(int w){ return __uint_as_float(((unsigned)w) << 16); }
__device__ __forceinline__ float bf_hi(int w){ return __uint_as_float(((unsigned)w) & 0xffff0000u); }
__device__ __forceinline__ int cvtpk(float lo, float hi) {
    int r;
    asm("v_cvt_pk_bf16_f32 %0, %1, %2" : "=v"(r) : "v"(lo), "v"(hi));
    return r;
}
__device__ __forceinline__ unsigned short bf16r(float x){
    unsigned int u = __float_as_uint(x);
    u += 0x7fffu + ((u >> 16) & 1u);
    return (unsigned short)(u >> 16);
}
// 8 bf16 elems of tanh(L+R) packed straight into an MFMA A-fragment word-group
__device__ __forceinline__ bf16x8 tanh_frag(int4 lv, int4 rv) {
    int4 st;
    st.x = cvtpk(tanh_s(bf_lo(lv.x) + bf_lo(rv.x)), tanh_s(bf_hi(lv.x) + bf_hi(rv.x)));
    st.y = cvtpk(tanh_s(bf_lo(lv.y) + bf_lo(rv.y)), tanh_s(bf_hi(lv.y) + bf_hi(rv.y)));
    st.z = cvtpk(tanh_s(bf_lo(lv.z) + bf_lo(rv.z)), tanh_s(bf_hi(lv.z) + bf_hi(rv.z)));
    st.w = cvtpk(tanh_s(bf_lo(lv.w) + bf_lo(rv.w)), tanh_s(bf_hi(lv.w) + bf_hi(rv.w)));
    return __builtin_bit_cast(bf16x8, st);
}

__device__ __forceinline__ int row_start(int i) { return i * SEQ - (i * (i - 1)) / 2; }
__device__ __forceinline__ void pair_ij(int p, int& oi, int& oj) {
    double disc = 263169.0 - 8.0 * (double)p;   // (2S+1)^2 - 8p
    int i = (int)((513.0 - sqrt(disc)) * 0.5);
    if (i > 0 && row_start(i) > p) --i;
    while (row_start(i + 1) <= p) ++i;
    oi = i;
    oj = i + (p - row_start(i));
}

// ---------------- kernel 0: pack Bpk (fragment-ordered), fcwb, bc ----------------
// Bpk linear idx = ((k32*10 + f)*64 + lane)*8 + j -> W[n=f*16+(lane&15)][k=k32*32+(lane>>4)*8+j]
__global__ __launch_bounds__(256) void pack_kernel(
    const float* __restrict__ h2t_w, const float* __restrict__ h2h_w,
    const float* __restrict__ t2t_w, const float* __restrict__ h2t_b,
    const float* __restrict__ h2h_b, const float* __restrict__ t2t_b,
    const float* __restrict__ fc_w,
    unsigned short* __restrict__ Bpk, unsigned short* __restrict__ fcwb,
    float* __restrict__ bc)
{
    int idx = blockIdx.x * 256 + threadIdx.x;
    if (idx < N_BPK) {
        int j = idx & 7, lane = (idx >> 3) & 63, rest = idx >> 9;
        int f = rest % 10, k32 = rest / 10;
        int n = f * 16 + (lane & 15);
        int k = k32 * 32 + ((lane >> 4) << 3) + j;
        float v = 0.f;
        if (n < 2)        v = h2t_w[n * H + k];
        else if (n < 74)  v = h2h_w[(n - 2) * H + k];
        else if (n < 146) v = t2t_w[(n - 74) * H + k];
        Bpk[idx] = bf16r(v);
    } else if (idx < N_BPK + N_FCW) {
        int q = idx - N_BPK;
        int n = q / H, k = q % H;          // n in [0,1536): 0..767 -> Wl, 768.. -> Wr
        float v = (n < H) ? fc_w[(size_t)n * 2 * H + k]
                          : fc_w[(size_t)(n - H) * 2 * H + H + k];
        fcwb[q] = bf16r(v);
    } else if (idx < N_BPK + N_FCW + NOUTP) {
        int q = idx - N_BPK - N_FCW;
        float v = 0.f;
        if (q < 2)        v = h2t_b[q];
        else if (q < 74)  v = h2h_b[q - 2];
        else if (q < 146) v = t2t_b[q - 74];
        bc[q] = v;
    }
}

// ---------------- kernel 1: LB/RB = hidden @ fc_w (bf16 MFMA GEMM), pre-scaled by SCL ----------------
__global__ __launch_bounds__(256, 2) void lr_mfma(
    const float* __restrict__ hidden, const unsigned short* __restrict__ fcwb,
    const float* __restrict__ fc_b,
    unsigned short* __restrict__ LB, unsigned short* __restrict__ RB)
{
    __shared__ __align__(16) char sm[24576];          // A 8KB | B 16KB
    const int tid = threadIdx.x, l = tid & 63, w = tid >> 6;
    const int wm = w >> 1, wn = w & 1;
    const int m0 = blockIdx.x * 64, n0 = blockIdx.y * 128;
    f32x4 acc[2][4] = {};
    for (int c = 0; c < 12; ++c) {
        const int k0 = c * 64;
        #pragma unroll
        for (int it = 0; it < 2; ++it) {              // A: 64 rows x 64 k, cvt f32->bf16
            int idx = tid + it * 256;
            int row = idx >> 3, k8 = idx & 7;
            const float4* src = reinterpret_cast<const float4*>(hidden + (size_t)(m0 + row) * H + k0 + k8 * 8);
            float4 a = src[0], bq = src[1];
            int4 st;
            st.x = cvtpk(a.x, a.y);  st.y = cvtpk(a.z, a.w);
            st.z = cvtpk(bq.x, bq.y); st.w = cvtpk(bq.z, bq.w);
            *reinterpret_cast<int4*>(sm + row * 128 + ((k8 * 16) ^ ((row & 7) << 4))) = st;
        }
        #pragma unroll
        for (int it = 0; it < 4; ++it) {              // B: 128 rows x 64 k
            int idx = tid + it * 256;
            int row = idx >> 3, k8 = idx & 7;
            *reinterpret_cast<int4*>(sm + 8192 + row * 128 + ((k8 * 16) ^ ((row & 7) << 4))) =
                *reinterpret_cast<const int4*>(fcwb + (size_t)(n0 + row) * H + k0 + k8 * 8);
        }
        __syncthreads();
        #pragma unroll
        for (int kk = 0; kk < 2; ++kk) {
            const int sl = kk * 4 + (l >> 4);
            const int swz = (l & 7) << 4;
            bf16x8 af[2], bfr[4];
            #pragma unroll
            for (int a = 0; a < 2; ++a) {
                int row = 32 * wm + 16 * a + (l & 15);
                af[a] = *reinterpret_cast<const bf16x8*>(sm + row * 128 + ((sl * 16) ^ swz));
            }
            #pragma unroll
            for (int f = 0; f < 4; ++f) {
                int row = 64 * wn + 16 * f + (l & 15);
                bfr[f] = *reinterpret_cast<const bf16x8*>(sm + 8192 + row * 128 + ((sl * 16) ^ swz));
            }
            #pragma unroll
            for (int a = 0; a < 2; ++a)
                #pragma unroll
                for (int f = 0; f < 4; ++f)
                    acc[a][f] = __builtin_amdgcn_mfma_f32_16x16x32_bf16(af[a], bfr[f], acc[a][f], 0, 0, 0);
        }
        __syncthreads();
    }
    #pragma unroll
    for (int a = 0; a < 2; ++a)
        #pragma unroll
        for (int f = 0; f < 4; ++f)
            #pragma unroll
            for (int r = 0; r < 4; ++r) {
                int row = m0 + 32 * wm + 16 * a + 4 * (l >> 4) + r;
                int col = n0 + 64 * wn + 16 * f + (l & 15);
                float v = acc[a][f][r];
                if (n0 < H) LB[(size_t)row * H + col] = bf16r((v + fc_b[col]) * SCL);
                else        RB[(size_t)row * H + (col - H)] = bf16r(v * SCL);
            }
}

// ---------------- kernel 2: A-in-registers MFMA pair kernel ----------------
// block = 256 thr (4 waves), wave = 32 rows x 160 cols (acc 2x10), M-tile = 128, chunk = 64 k
// A: each lane computes tanh(L+R) directly into its own MFMA A-frags (no LDS for A).
// B: global->reg (early) -> LDS dbuf (write-late), 1 barrier/chunk.
__global__ __launch_bounds__(256, 3) void pair_mfma(
    const unsigned short* __restrict__ LB, const unsigned short* __restrict__ RB,
    const unsigned short* __restrict__ Bpk, const float* __restrict__ bc,
    float* __restrict__ out)
{
    __shared__ __align__(16) char sm[42624];
    // B buf0 [0,20480) | buf1 [20480,40960) | iOf [40960,41472) | jOf [41472,41984) | bc_s [41984,42624)
    // epilogue: scores [32][172] f32 alias at [0,22016)
    int*   iOf  = reinterpret_cast<int*>(sm + 40960);
    int*   jOf  = reinterpret_cast<int*>(sm + 41472);
    float* bc_s = reinterpret_cast<float*>(sm + 41984);

    const int tid = threadIdx.x, l = tid & 63, w = tid >> 6;
    const int b = blockIdx.y, p0 = blockIdx.x * 128;

    if (tid < 128) {
        int i, j; pair_ij(p0 + tid, i, j);
        iOf[tid] = i * H; jOf[tid] = j * H;
    }
    if (tid < NOUTP) bc_s[tid] = bc[tid];
    __syncthreads();

    const unsigned short* LBb = LB + (size_t)b * SEQ * H;
    const unsigned short* RBb = RB + (size_t)b * SEQ * H;
    const int row0 = 32 * w + (l & 15);           // m=0 row, m=1 row = row0+16
    const int kb = (l >> 4) << 3;                 // lane k-seg base (bf16 units)
    const unsigned short* lp0 = LBb + iOf[row0] + kb;
    const unsigned short* rp0 = RBb + jOf[row0] + kb;
    const unsigned short* lp1 = LBb + iOf[row0 + 16] + kb;
    const unsigned short* rp1 = RBb + jOf[row0 + 16] + kb;

    const int4* bsrc = reinterpret_cast<const int4*>(Bpk);
    f32x4 acc[2][10] = {};

    // prologue: B(0)->regs->buf0 ; L/R(0)->regs
    int4 nb0 = bsrc[tid], nb1 = bsrc[tid + 256], nb2 = bsrc[tid + 512],
         nb3 = bsrc[tid + 768], nb4 = bsrc[tid + 1024];
    int4 lA0 = *reinterpret_cast<const int4*>(lp0);        // m0 kk0
    int4 lA1 = *reinterpret_cast<const int4*>(lp0 + 32);   // m0 kk1
    int4 lB0 = *reinterpret_cast<const int4*>(lp1);        // m1 kk0
    int4 lB1 = *reinterpret_cast<const int4*>(lp1 + 32);   // m1 kk1
    int4 rA0 = *reinterpret_cast<const int4*>(rp0);
    int4 rA1 = *reinterpret_cast<const int4*>(rp0 + 32);
    int4 rB0 = *reinterpret_cast<const int4*>(rp1);
    int4 rB1 = *reinterpret_cast<const int4*>(rp1 + 32);
    {
        int4* bw = reinterpret_cast<int4*>(sm);
        bw[tid] = nb0; bw[tid + 256] = nb1; bw[tid + 512] = nb2;
        bw[tid + 768] = nb3; bw[tid + 1024] = nb4;
    }
    __syncthreads();

    #pragma unroll 2
    for (int c = 0; c < 11; ++c) {
        // 1) issue next B chunk -> regs (oldest in flight; ~full chunk of latency)
        const int4* bn = bsrc + (c + 1) * 1280;
        nb0 = bn[tid]; nb1 = bn[tid + 256]; nb2 = bn[tid + 512];
        nb3 = bn[tid + 768]; nb4 = bn[tid + 1024];
        // 2) A-frags: tanh straight into registers (current chunk's L/R already arrived)
        bf16x8 a00 = tanh_frag(lA0, rA0);   // m0 kk0
        bf16x8 a10 = tanh_frag(lB0, rB0);   // m1 kk0
        bf16x8 a01 = tanh_frag(lA1, rA1);   // m0 kk1
        bf16x8 a11 = tanh_frag(lB1, rB1);   // m1 kk1
        // 3) issue next chunk L/R (regs reusable after step 2; latency hidden by MFMA+barrier)
        const int co = (c + 1) * 64;
        lA0 = *reinterpret_cast<const int4*>(lp0 + co);
        lA1 = *reinterpret_cast<const int4*>(lp0 + co + 32);
        lB0 = *reinterpret_cast<const int4*>(lp1 + co);
        lB1 = *reinterpret_cast<const int4*>(lp1 + co + 32);
        rA0 = *reinterpret_cast<const int4*>(rp0 + co);
        rA1 = *reinterpret_cast<const int4*>(rp0 + co + 32);
        rB0 = *reinterpret_cast<const int4*>(rp1 + co);
        rB1 = *reinterpret_cast<const int4*>(rp1 + co + 32);
        // 4) MFMA on buf c (B frags from LDS, linear lane*16 reads)
        const char* bufc = sm + ((c & 1) ? 20480 : 0);
        #pragma unroll
        for (int f = 0; f < 10; ++f) {
            bf16x8 bf0 = *reinterpret_cast<const bf16x8*>(bufc + (f * 64 + l) * 16);
            acc[0][f] = __builtin_amdgcn_mfma_f32_16x16x32_bf16(a00, bf0, acc[0][f], 0, 0, 0);
            acc[1][f] = __builtin_amdgcn_mfma_f32_16x16x32_bf16(a10, bf0, acc[1][f], 0, 0, 0);
        }
        #pragma unroll
        for (int f = 0; f < 10; ++f) {
            bf16x8 bf1 = *reinterpret_cast<const bf16x8*>(bufc + ((10 + f) * 64 + l) * 16);
            acc[0][f] = __builtin_amdgcn_mfma_f32_16x16x32_bf16(a01, bf1, acc[0][f], 0, 0, 0);
            acc[1][f] = __builtin_amdgcn_mfma_f32_16x16x32_bf16(a11, bf1, acc[1][f], 0, 0, 0);
        }
        // 5) write-late: B(c+1) regs -> buf^1 (vmcnt counted wait; arrived by now)
        int4* bufn = reinterpret_cast<int4*>(sm + (((c + 1) & 1) ? 20480 : 0));
        bufn[tid] = nb0; bufn[tid + 256] = nb1; bufn[tid + 512] = nb2;
        bufn[tid + 768] = nb3; bufn[tid + 1024] = nb4;
        // 6) one barrier per chunk
        __syncthreads();
    }
    {   // peeled chunk 11 (no prefetch)
        bf16x8 a00 = tanh_frag(lA0, rA0);
        bf16x8 a10 = tanh_frag(lB0, rB0);
        bf16x8 a01 = tanh_frag(lA1, rA1);
        bf16x8 a11 = tanh_frag(lB1, rB1);
        const char* bufc = sm + 20480;          // 11&1 = 1
        #pragma unroll
        for (int f = 0; f < 10; ++f) {
            bf16x8 bf0 = *reinterpret_cast<const bf16x8*>(bufc + (f * 64 + l) * 16);
            acc[0][f] = __builtin_amdgcn_mfma_f32_16x16x32_bf16(a00, bf0, acc[0][f], 0, 0, 0);
            acc[1][f] = __builtin_amdgcn_mfma_f32_16x16x32_bf16(a10, bf0, acc[1][f], 0, 0, 0);
        }
        #pragma unroll
        for (int f = 0; f < 10; ++f) {
            bf16x8 bf1 = *reinterpret_cast<const bf16x8*>(bufc + ((10 + f) * 64 + l) * 16);
            acc[0][f] = __builtin_amdgcn_mfma_f32_16x16x32_bf16(a01, bf1, acc[0][f], 0, 0, 0);
            acc[1][f] = __builtin_amdgcn_mfma_f32_16x16x32_bf16(a11, bf1, acc[1][f], 0, 0, 0);
        }
    }
    __syncthreads();   // all MFMA LDS reads done before score slab aliases buf space

    // epilogue: 4 steps; wave s dumps its 32 rows -> slab, all 4 waves do bias/softmax/writes
    float* scw = reinterpret_cast<float*>(sm);               // [32][172]
    for (int s = 0; s < 4; ++s) {
        if (w == s) {
            #pragma unroll
            for (int m = 0; m < 2; ++m)
                #pragma unroll
                for (int f = 0; f < 10; ++f)
                    #pragma unroll
                    for (int r = 0; r < 4; ++r) {
                        int rl = 16 * m + 4 * (l >> 4) + r;
                        scw[rl * 172 + f * 16 + (l & 15)] = acc[m][f][r];
                    }
        }
        __syncthreads();
        if (tid < 64) {                                      // h2t: 32 rows x 2
            int rl = tid >> 1, tt = tid & 1;
            int p = p0 + 32 * s + rl;
            out[((size_t)b * NPAIR + p) * 2 + tt] = scw[rl * 172 + tt] + bc_s[tt];
        }
        #pragma unroll
        for (int it = 0; it < 6; ++it) {                     // 32 rows x 48 triples
            int item = it * 256 + tid;
            int rl = item & 31, rr = item >> 5;
            int ob = 2 + rr * 3;
            float l0 = scw[rl * 172 + ob + 0] + bc_s[ob + 0];
            float l1 = scw[rl * 172 + ob + 1] + bc_s[ob + 1];
            float l2 = scw[rl * 172 + ob + 2] + bc_s[ob + 2];
            float mx = fmaxf(l0, fmaxf(l1, l2));
            float e0 = __expf(l0 - mx), e1 = __expf(l1 - mx), e2 = __expf(l2 - mx);
            float inv = __fdividef(1.0f, e0 + e1 + e2);
            int p = p0 + 32 * s + rl;
            size_t base = (rr < 24)
                ? (size_t)OFF_H2H + ((size_t)(b * 24 + rr) * NPAIR + p) * 3
                : (size_t)OFF_T2T + ((size_t)(b * 24 + rr - 24) * NPAIR + p) * 3;
            out[base + 0] = e0 * inv;
            out[base + 1] = e1 * inv;
            out[base + 2] = e2 * inv;
        }
        __syncthreads();
    }
}

extern "C" void kernel_launch(void* const* d_in, const int* in_sizes, int n_in,
                              void* d_out, int out_size, void* d_ws, size_t ws_size,
                              hipStream_t stream) {
    const float* hidden = (const float*)d_in[0];
    const float* fc_w   = (const float*)d_in[1];
    const float* fc_b   = (const float*)d_in[2];
    const float* h2t_w  = (const float*)d_in[3];
    const float* h2t_b  = (const float*)d_in[4];
    const float* h2h_w  = (const float*)d_in[5];
    const float* h2h_b  = (const float*)d_in[6];
    const float* t2t_w  = (const float*)d_in[7];
    const float* t2t_b  = (const float*)d_in[8];

    char* wsb = (char*)d_ws;
    unsigned short* LBw  = (unsigned short*)(wsb);              // 1024*768 bf16 = 1.5 MB
    unsigned short* RBw  = (unsigned short*)(wsb + 1572864);    // 1.5 MB
    unsigned short* Bpk  = (unsigned short*)(wsb + 3145728);    // 240 KB
    unsigned short* fcwb = (unsigned short*)(wsb + 3391488);    // 2.25 MB
    float*          bc   = (float*)        (wsb + 5750784);     // 640 B

    float* out = (float*)d_out;

    pack_kernel<<<(N_BPK + N_FCW + NOUTP + 255) / 256, 256, 0, stream>>>(
        h2t_w, h2h_w, t2t_w, h2t_b, h2h_b, t2t_b, fc_w, Bpk, fcwb, bc);
    lr_mfma<<<dim3(16, 12), 256, 0, stream>>>(hidden, fcwb, fc_b, LBw, RBw);
    pair_mfma<<<dim3(NPAIR / 128, 4), 256, 0, stream>>>(LBw, RBw, Bpk, bc, out);
}